// Round 8
// baseline (797.068 us; speedup 1.0000x reference)
//
#include <hip/hip_runtime.h>
#include <hip/hip_fp16.h>
#include <math.h>

#define DFEAT 128
#define BK 128            // dst nodes per bucket (64 KB fp32 LDS tile)
#define CH 4096           // edges per histogram/scatter chunk
typedef unsigned long long u64;
typedef unsigned int u32;

// ---- kernel 1: fused elu (emb2 fp16) + per-chunk bucket histogram ----
// blocks [0, nb): chunk b histograms dst>>7 into LDS, writes hist[k*nb + b]
// blocks [nb, ..): emb2[i] = fp16( 2*elu(x[i]*w[i%D]) )
__global__ void fused_elu_hist_kernel(const float* __restrict__ x,
                                      const float* __restrict__ w,
                                      __half* __restrict__ emb2, int total4,
                                      const int* __restrict__ dst, int E,
                                      u32* __restrict__ hist, int nb, int NB) {
    if ((int)blockIdx.x >= nb) {
        int idx = (blockIdx.x - nb) * blockDim.x + threadIdx.x;
        if (idx >= total4) return;
        float4 xv = ((const float4*)x)[idx];
        float4 wv = ((const float4*)w)[idx & (DFEAT / 4 - 1)];
        float a, r0, r1, r2, r3;
        a = xv.x * wv.x; r0 = 2.0f * (a > 0.0f ? a : (__expf(a) - 1.0f));
        a = xv.y * wv.y; r1 = 2.0f * (a > 0.0f ? a : (__expf(a) - 1.0f));
        a = xv.z * wv.z; r2 = 2.0f * (a > 0.0f ? a : (__expf(a) - 1.0f));
        a = xv.w * wv.w; r3 = 2.0f * (a > 0.0f ? a : (__expf(a) - 1.0f));
        __half2 h01 = __floats2half2_rn(r0, r1);
        __half2 h23 = __floats2half2_rn(r2, r3);
        uint2 pk;
        pk.x = *(u32*)&h01;
        pk.y = *(u32*)&h23;
        ((uint2*)emb2)[idx] = pk;
    } else {
        __shared__ u32 cnt[512];
        int b = blockIdx.x;
        int t = threadIdx.x;
        cnt[t] = 0; cnt[t + 256] = 0;
        __syncthreads();
        int g0 = b * (CH / 4);                      // first int4 group of chunk
        #pragma unroll
        for (int i = 0; i < CH / 4 / 256; ++i) {
            int g = g0 + t + i * 256;
            if (g * 4 + 3 < E) {
                int4 d4 = ((const int4*)dst)[g];
                atomicAdd(&cnt[d4.x >> 7], 1u);
                atomicAdd(&cnt[d4.y >> 7], 1u);
                atomicAdd(&cnt[d4.z >> 7], 1u);
                atomicAdd(&cnt[d4.w >> 7], 1u);
            } else {
                for (int e = g * 4; e < E; ++e) atomicAdd(&cnt[dst[e] >> 7], 1u);
            }
        }
        __syncthreads();
        for (int k = t; k < NB; k += 256) hist[(size_t)k * nb + b] = cnt[k];
    }
}

// ---- kernel 2: per-bucket exclusive scan over chunks ----
__global__ void scanA_kernel(u32* __restrict__ hist, u32* __restrict__ totals,
                             int nb) {
    __shared__ u32 s[256];
    int k = blockIdx.x;
    int t = threadIdx.x;
    u32 v = (t < nb) ? hist[(size_t)k * nb + t] : 0u;
    s[t] = v;
    __syncthreads();
    for (int off = 1; off < 256; off <<= 1) {
        u32 add = (t >= off) ? s[t - off] : 0u;
        __syncthreads();
        s[t] += add;
        __syncthreads();
    }
    if (t < nb) hist[(size_t)k * nb + t] = s[t] - v;   // exclusive
    if (t == 255) totals[k] = s[255];
}

// ---- kernel 3: exclusive scan over bucket totals -> bases ----
__global__ void scanB_kernel(const u32* __restrict__ totals,
                             u32* __restrict__ bases, int NB) {
    __shared__ u32 s[512];
    int t = threadIdx.x;
    u32 v = (t < NB) ? totals[t] : 0u;
    s[t] = v;
    __syncthreads();
    for (int off = 1; off < 512; off <<= 1) {
        u32 add = (t >= off) ? s[t - off] : 0u;
        __syncthreads();
        s[t] += add;
        __syncthreads();
    }
    if (t < NB) bases[t] = s[t] - v;
    if (t == NB - 1) bases[NB] = s[t];
}

// ---- kernel 4: scatter packed (src<<7 | dstLocal) into bucket-sorted order ----
__global__ void scatter_sort_kernel(const int* __restrict__ src,
                                    const int* __restrict__ dst, int E,
                                    const u32* __restrict__ hist,
                                    const u32* __restrict__ bases,
                                    u32* __restrict__ sorted, int nb, int NB) {
    __shared__ u32 cnt[512];
    int b = blockIdx.x;
    int t = threadIdx.x;
    for (int k = t; k < NB; k += 256) cnt[k] = bases[k] + hist[(size_t)k * nb + b];
    __syncthreads();
    int g0 = b * (CH / 4);
    #pragma unroll
    for (int i = 0; i < CH / 4 / 256; ++i) {
        int g = g0 + t + i * 256;
        if (g * 4 + 3 < E) {
            int4 s4 = ((const int4*)src)[g];
            int4 d4 = ((const int4*)dst)[g];
            u32 p;
            p = atomicAdd(&cnt[d4.x >> 7], 1u); sorted[p] = ((u32)s4.x << 7) | ((u32)d4.x & 127u);
            p = atomicAdd(&cnt[d4.y >> 7], 1u); sorted[p] = ((u32)s4.y << 7) | ((u32)d4.y & 127u);
            p = atomicAdd(&cnt[d4.z >> 7], 1u); sorted[p] = ((u32)s4.z << 7) | ((u32)d4.z & 127u);
            p = atomicAdd(&cnt[d4.w >> 7], 1u); sorted[p] = ((u32)s4.w << 7) | ((u32)d4.w & 127u);
        } else {
            for (int e = g * 4; e < E; ++e) {
                u32 p = atomicAdd(&cnt[dst[e] >> 7], 1u);
                sorted[p] = ((u32)src[e] << 7) | ((u32)dst[e] & 127u);
            }
        }
    }
}

// ---- kernel 5: per-bucket gather + LDS fp32 tile reduce, write out once ----
// One block per bucket, 512 threads (8 waves). Full wave per edge: lane owns
// one u32 (2 fp16 cols); tile adds are 2-way bank-aliased (free). Unroll-4
// keeps 4 independent 256B row loads in flight per wave.
__global__ void gather_tile_kernel(const u32* __restrict__ embu,  // N*64 u32
                                   const u32* __restrict__ sorted,
                                   const u32* __restrict__ bases,
                                   float* __restrict__ out, int N) {
    __shared__ float tile[BK * DFEAT];          // 64 KB
    int k = blockIdx.x;
    int t = threadIdx.x;
    int w = t >> 6;
    int lane = t & 63;
    #pragma unroll
    for (int i = 0; i < BK * DFEAT / 512; ++i) tile[t + i * 512] = 0.0f;
    __syncthreads();
    int begin = (int)bases[k];
    int end = (int)bases[k + 1];
    int e = begin + w;
    for (; e + 24 < end; e += 32) {
        u32 p0 = sorted[e];
        u32 p1 = sorted[e + 8];
        u32 p2 = sorted[e + 16];
        u32 p3 = sorted[e + 24];
        u32 h0 = embu[(size_t)(p0 >> 7) * 64u + (u32)lane];
        u32 h1 = embu[(size_t)(p1 >> 7) * 64u + (u32)lane];
        u32 h2 = embu[(size_t)(p2 >> 7) * 64u + (u32)lane];
        u32 h3 = embu[(size_t)(p3 >> 7) * 64u + (u32)lane];
        float2 f0 = __half22float2(*(__half2*)&h0);
        float2 f1 = __half22float2(*(__half2*)&h1);
        float2 f2 = __half22float2(*(__half2*)&h2);
        float2 f3 = __half22float2(*(__half2*)&h3);
        float* tp0 = &tile[(p0 & 127u) * DFEAT + lane * 2];
        float* tp1 = &tile[(p1 & 127u) * DFEAT + lane * 2];
        float* tp2 = &tile[(p2 & 127u) * DFEAT + lane * 2];
        float* tp3 = &tile[(p3 & 127u) * DFEAT + lane * 2];
        atomicAdd(tp0 + 0, f0.x); atomicAdd(tp0 + 1, f0.y);
        atomicAdd(tp1 + 0, f1.x); atomicAdd(tp1 + 1, f1.y);
        atomicAdd(tp2 + 0, f2.x); atomicAdd(tp2 + 1, f2.y);
        atomicAdd(tp3 + 0, f3.x); atomicAdd(tp3 + 1, f3.y);
    }
    for (; e < end; e += 8) {
        u32 p0 = sorted[e];
        u32 h0 = embu[(size_t)(p0 >> 7) * 64u + (u32)lane];
        float2 f0 = __half22float2(*(__half2*)&h0);
        float* tp0 = &tile[(p0 & 127u) * DFEAT + lane * 2];
        atomicAdd(tp0 + 0, f0.x); atomicAdd(tp0 + 1, f0.y);
    }
    __syncthreads();
    int valid = min(BK, N - k * BK);
    int cnt4 = valid * (DFEAT / 4);
    float4* o4 = (float4*)out + (size_t)k * BK * (DFEAT / 4);
    const float4* t4 = (const float4*)tile;
    for (int i = t; i < cnt4; i += 512) o4[i] = t4[i];
}

// ---- fallback: fused elu + fp32 atomic scatter ----
__global__ void scatter_fused_kernel(const float* __restrict__ x,
                                     const float* __restrict__ w,
                                     const int* __restrict__ src,
                                     const int* __restrict__ dst,
                                     float* __restrict__ out, int E) {
    int t = blockIdx.x * blockDim.x + threadIdx.x;
    int edge = t >> 5;
    int lane = t & 31;
    if (edge >= E) return;
    int s = src[edge];
    int d = dst[edge];
    float4 xv = ((const float4*)(x + (size_t)s * DFEAT))[lane];
    float4 wv = ((const float4*)w)[lane];
    float4 v;
    float a;
    a = xv.x * wv.x; v.x = 2.0f * (a > 0.0f ? a : (__expf(a) - 1.0f));
    a = xv.y * wv.y; v.y = 2.0f * (a > 0.0f ? a : (__expf(a) - 1.0f));
    a = xv.z * wv.z; v.z = 2.0f * (a > 0.0f ? a : (__expf(a) - 1.0f));
    a = xv.w * wv.w; v.w = 2.0f * (a > 0.0f ? a : (__expf(a) - 1.0f));
    float* op = out + (size_t)d * DFEAT + lane * 4;
    unsafeAtomicAdd(op + 0, v.x);
    unsafeAtomicAdd(op + 1, v.y);
    unsafeAtomicAdd(op + 2, v.z);
    unsafeAtomicAdd(op + 3, v.w);
}

extern "C" void kernel_launch(void* const* d_in, const int* in_sizes, int n_in,
                              void* d_out, int out_size, void* d_ws, size_t ws_size,
                              hipStream_t stream) {
    const float* x   = (const float*)d_in[0];   // graph_embedding [N, 128]
    const float* w   = (const float*)d_in[1];   // weight [1, 128]
    const int*   src = (const int*)d_in[3];     // src [E]
    const int*   dst = (const int*)d_in[4];     // dst [E]
    float* out = (float*)d_out;

    const int ND = in_sizes[0];          // N * 128
    const int N  = ND / DFEAT;           // 50000
    const int E  = in_sizes[2];          // 800000

    const int NB = (N + BK - 1) / BK;    // 391 buckets
    const int nb = (E + CH - 1) / CH;    // 196 chunks

    size_t emb_bytes    = (((size_t)N * DFEAT) * sizeof(__half) + 63) & ~(size_t)63;
    size_t hist_bytes   = ((size_t)NB * nb * sizeof(u32) + 63) & ~(size_t)63;
    size_t totals_bytes = ((size_t)NB * sizeof(u32) + 63) & ~(size_t)63;
    size_t bases_bytes  = ((size_t)(NB + 1) * sizeof(u32) + 63) & ~(size_t)63;
    size_t sorted_bytes = (size_t)E * sizeof(u32);
    size_t total = emb_bytes + hist_bytes + totals_bytes + bases_bytes + sorted_bytes;

    bool ok = (ws_size >= total) && (nb <= 256) && (NB <= 512) && (N <= (1 << 24));

    if (ok) {
        char* p = (char*)d_ws;
        __half* emb2   = (__half*)p;  p += emb_bytes;
        u32*    hist   = (u32*)p;     p += hist_bytes;
        u32*    totals = (u32*)p;     p += totals_bytes;
        u32*    bases  = (u32*)p;     p += bases_bytes;
        u32*    sorted = (u32*)p;

        int total4    = ND / 4;
        int eluBlocks = (total4 + 255) / 256;
        fused_elu_hist_kernel<<<nb + eluBlocks, 256, 0, stream>>>(
            x, w, emb2, total4, dst, E, hist, nb, NB);
        scanA_kernel<<<NB, 256, 0, stream>>>(hist, totals, nb);
        scanB_kernel<<<1, 512, 0, stream>>>(totals, bases, NB);
        scatter_sort_kernel<<<nb, 256, 0, stream>>>(src, dst, E, hist, bases, sorted, nb, NB);
        gather_tile_kernel<<<NB, 512, 0, stream>>>((const u32*)emb2, sorted, bases, out, N);
    } else {
        hipMemsetAsync(d_out, 0, (size_t)out_size * sizeof(float), stream);
        long long threads = (long long)E * 32;
        scatter_fused_kernel<<<(int)((threads + 255) / 256), 256, 0, stream>>>(x, w, src, dst, out, E);
    }
}